// Round 1
// baseline (983.493 us; speedup 1.0000x reference)
//
#include <hip/hip_runtime.h>
#include <stdint.h>

#define T_TOK 8192
#define HID   4096
#define NOUT  6144
#define S_SLOTS 8
#define TPAD_MAX 9216   // 8192 + 8*128 worst-case per-slot padding

typedef __attribute__((ext_vector_type(8))) short bf16x8;
typedef __attribute__((ext_vector_type(4))) float f32x4;

__device__ __forceinline__ unsigned short f2bf(float f) {
  union { float f; unsigned u; } v; v.f = f;
  unsigned r = v.u + 0x7FFFu + ((v.u >> 16) & 1u);   // RNE
  return (unsigned short)(r >> 16);
}

__device__ __forceinline__ f32x4 mfma32(bf16x8 a, bf16x8 b, f32x4 c) {
  return __builtin_amdgcn_mfma_f32_16x16x32_bf16(a, b, c, 0, 0, 0);
}

__device__ __forceinline__ void glds16(const void* g, void* l) {
  __builtin_amdgcn_global_load_lds(
      (const __attribute__((address_space(1))) unsigned int*)g,
      (__attribute__((address_space(3))) unsigned int*)l, 16, 0, 0);
}

// ---------------- sort tokens by slot, pad each slot range to 128 ----------------
__global__ void k_sort(const int* __restrict__ t2s, int* __restrict__ perm,
                       int* __restrict__ slotarr, int* __restrict__ meta) {
  __shared__ int cnt[8], cur[8], padoff[9];
  int tid = threadIdx.x;
  if (tid < 8) cnt[tid] = 0;
  __syncthreads();
  for (int t = tid; t < T_TOK; t += 256) atomicAdd(&cnt[t2s[t]], 1);
  __syncthreads();
  if (tid == 0) {
    int o = 0;
    for (int s = 0; s < 8; ++s) { padoff[s] = o; o += ((cnt[s] + 127) >> 7) << 7; }
    padoff[8] = o;
    meta[0] = o;  // Tpad
  }
  __syncthreads();
  if (tid < 8) cur[tid] = padoff[tid];
  int Tpad = padoff[8];
  // init: every padded row = dummy(-1) with its tile's slot id
  for (int p = tid; p < TPAD_MAX; p += 256) {
    int s = 0;
    if (p < Tpad) { while (s < 7 && p >= padoff[s + 1]) ++s; }
    perm[p] = -1;
    slotarr[p] = s;
  }
  __syncthreads();
  for (int t = tid; t < T_TOK; t += 256) {
    int s = t2s[t];
    int pos = atomicAdd(&cur[s], 1);
    perm[pos] = t;
  }
}

// ---------------- f32 -> bf16 bulk convert (n8 = #groups of 8) ----------------
__global__ void k_convert(const float* __restrict__ src, unsigned short* __restrict__ dst, int n8) {
  int i = blockIdx.x * blockDim.x + threadIdx.x;
  int stride = gridDim.x * blockDim.x;
  for (; i < n8; i += stride) {
    const f32x4* s = (const f32x4*)src + (size_t)i * 2;
    f32x4 a = s[0], b = s[1];
    bf16x8 o;
    o[0]=(short)f2bf(a[0]); o[1]=(short)f2bf(a[1]); o[2]=(short)f2bf(a[2]); o[3]=(short)f2bf(a[3]);
    o[4]=(short)f2bf(b[0]); o[5]=(short)f2bf(b[1]); o[6]=(short)f2bf(b[2]); o[7]=(short)f2bf(b[3]);
    *((bf16x8*)dst + i) = o;
  }
}

// ---------------- x: gather by perm + convert; zero dummy rows ----------------
__global__ void k_convert_x(const float* __restrict__ x, const int* __restrict__ perm,
                            const int* __restrict__ meta, unsigned short* __restrict__ xb) {
  int p = blockIdx.x;
  int Tpad = meta[0];
  int t = (p < Tpad) ? perm[p] : -1;
  bf16x8* drow = (bf16x8*)(xb + (size_t)p * HID);
  int tid = threadIdx.x;
  if (t >= 0) {
    const f32x4* srow = (const f32x4*)(x + (size_t)t * HID);
    for (int j = tid; j < HID / 8; j += 256) {
      f32x4 a = srow[j * 2], b = srow[j * 2 + 1];
      bf16x8 o;
      o[0]=(short)f2bf(a[0]); o[1]=(short)f2bf(a[1]); o[2]=(short)f2bf(a[2]); o[3]=(short)f2bf(a[3]);
      o[4]=(short)f2bf(b[0]); o[5]=(short)f2bf(b[1]); o[6]=(short)f2bf(b[2]); o[7]=(short)f2bf(b[3]);
      drow[j] = o;
    }
  } else {
    bf16x8 z = {0,0,0,0,0,0,0,0};
    for (int j = tid; j < HID / 8; j += 256) drow[j] = z;
  }
}

// ---------------- Bq|Bk|Bv -> concatenated bf16 [S][6144][16] ----------------
__global__ void k_convert_B(const float* __restrict__ Bq, const float* __restrict__ Bk,
                            const float* __restrict__ Bv, unsigned short* __restrict__ Bb) {
  int i = blockIdx.x * blockDim.x + threadIdx.x;
  int stride = gridDim.x * blockDim.x;
  const int total = S_SLOTS * NOUT * 16;
  for (; i < total; i += stride) {
    int s = i / (NOUT * 16);
    int rem = i - s * (NOUT * 16);
    int col = rem >> 4, r = rem & 15;
    float v;
    if (col < 4096)      v = Bq[((size_t)s * 4096 + col) * 16 + r];
    else if (col < 5120) v = Bk[((size_t)s * 1024 + (col - 4096)) * 16 + r];
    else                 v = Bv[((size_t)s * 1024 + (col - 5120)) * 16 + r];
    Bb[i] = f2bf(v);
  }
}

// ---------------- a[p, 48] = scaling[s] * xb[p] @ A[s]^T   (bf16 out) ----------------
// 256 threads = 4 waves, each wave does K/4, LDS reduce. 32 tokens per block.
__global__ __launch_bounds__(256) void k_loraA(
    const unsigned short* __restrict__ xb, const unsigned short* __restrict__ Ab,
    const float* __restrict__ scaling, const int* __restrict__ slotarr,
    const int* __restrict__ meta, unsigned short* __restrict__ abf) {
  int p0 = blockIdx.x * 32;
  int Tpad = meta[0];
  if (p0 >= Tpad) return;
  __shared__ float red[3][64 * 24];
  int tid = threadIdx.x, lane = tid & 63, wid = tid >> 6;
  int s = slotarr[p0];
  const unsigned short* A_s = Ab + (size_t)s * 48 * HID;
  int r = lane & 15, g = lane >> 4;
  f32x4 acc[2][3] = {};
  int kbase = wid * (HID / 4);
  for (int k = kbase; k < kbase + HID / 4; k += 32) {
    const unsigned short* xk = xb + (size_t)p0 * HID + k + g * 8;
    bf16x8 a0 = *(const bf16x8*)(xk + (size_t)r * HID);
    bf16x8 a1 = *(const bf16x8*)(xk + (size_t)(r + 16) * HID);
    const unsigned short* ak = A_s + k + g * 8;
    bf16x8 b0 = *(const bf16x8*)(ak + (size_t)r * HID);
    bf16x8 b1 = *(const bf16x8*)(ak + (size_t)(r + 16) * HID);
    bf16x8 b2 = *(const bf16x8*)(ak + (size_t)(r + 32) * HID);
    acc[0][0] = mfma32(a0, b0, acc[0][0]);
    acc[0][1] = mfma32(a0, b1, acc[0][1]);
    acc[0][2] = mfma32(a0, b2, acc[0][2]);
    acc[1][0] = mfma32(a1, b0, acc[1][0]);
    acc[1][1] = mfma32(a1, b1, acc[1][1]);
    acc[1][2] = mfma32(a1, b2, acc[1][2]);
  }
  if (wid > 0) {
    float* dst = &red[wid - 1][lane * 24];
    for (int m = 0; m < 2; ++m)
      for (int n = 0; n < 3; ++n)
        for (int reg = 0; reg < 4; ++reg) dst[(m * 3 + n) * 4 + reg] = acc[m][n][reg];
  }
  __syncthreads();
  if (wid == 0) {
    float sc = scaling[s];
    for (int m = 0; m < 2; ++m)
      for (int n = 0; n < 3; ++n)
        for (int reg = 0; reg < 4; ++reg) {
          int idx = (m * 3 + n) * 4 + reg;
          float v = acc[m][n][reg] + red[0][lane * 24 + idx] + red[1][lane * 24 + idx] +
                    red[2][lane * 24 + idx];
          int row = p0 + m * 16 + g * 4 + reg;
          abf[(size_t)row * 48 + n * 16 + r] = f2bf(v * sc);
        }
  }
}

// ---------------- main GEMM: 128x128 tile, BK=64, fused LoRA K=16 tail ----------------
__global__ __launch_bounds__(256, 2) void k_gemm(
    const unsigned short* __restrict__ xb, const unsigned short* __restrict__ Wb,
    const unsigned short* __restrict__ abf, const unsigned short* __restrict__ Bb,
    const int* __restrict__ perm, const int* __restrict__ slotarr,
    const int* __restrict__ meta, float* __restrict__ out) {
  __shared__ __align__(16) unsigned short As[128 * 64];
  __shared__ __align__(16) unsigned short Bs[128 * 64];
  __shared__ __align__(16) unsigned short As2[128 * 16];
  __shared__ __align__(16) unsigned short Bs2[128 * 16];

  const int Tpad = meta[0];
  const int nblocks = (Tpad >> 7) * 48;
  int bid = (int)blockIdx.x;
  int swz = (bid & 7) * 432 + (bid >> 3);  // bijective XCD swizzle on 3456
  if (swz >= nblocks) return;
  const int bm = swz / 48, bn = swz % 48;

  const int tid = threadIdx.x, lane = tid & 63;
  const int wm = tid >> 7, wn = (tid >> 6) & 1;
  const size_t rowA0 = (size_t)bm << 7;
  const size_t rowB0 = (size_t)bn << 7;
  const int s_tile = slotarr[rowA0];
  const int tgt = (bn >= 40) ? 2 : (bn >= 32) ? 1 : 0;

  // one-time stage of LoRA fold tiles (a-slice and B-slice), 128 rows x 16 bf16 each
  {
    int i = tid, row = i >> 1, half = i & 1;
    const unsigned short* ga = abf + (rowA0 + row) * 48 + tgt * 16 + half * 8;
    glds16(ga, (char*)As2 + ((i & ~63) << 4));
    const unsigned short* gb = Bb + ((size_t)s_tile * NOUT + ((size_t)bn << 7) + row) * 16 + half * 8;
    glds16(gb, (char*)Bs2 + ((i & ~63) << 4));
  }

  f32x4 acc[4][4] = {};

  for (int k0 = 0; k0 < HID; k0 += 64) {
    __syncthreads();  // prior compute done (also drains the As2/Bs2 stage on iter 0)
    #pragma unroll
    for (int it = 0; it < 4; ++it) {
      int i = it * 256 + tid;
      int row = i >> 3;
      int ksrc = ((i & 7) ^ (row & 7)) << 3;  // inverse XOR-swizzled global source
      glds16(xb + (rowA0 + row) * (size_t)HID + k0 + ksrc, (char*)As + ((i & ~63) << 4));
      glds16(Wb + (rowB0 + row) * (size_t)HID + k0 + ksrc, (char*)Bs + ((i & ~63) << 4));
    }
    __syncthreads();  // vmcnt(0) drain: tiles ready
    #pragma unroll
    for (int c = 0; c < 2; ++c) {
      bf16x8 af[4], bfr[4];
      #pragma unroll
      for (int m = 0; m < 4; ++m) {
        int row = (wm << 6) + (m << 4) + (lane & 15);
        int j = ((c << 2) + (lane >> 4)) ^ (lane & 7);  // swizzled read
        af[m] = *(const bf16x8*)((const char*)As + row * 128 + j * 16);
      }
      #pragma unroll
      for (int n = 0; n < 4; ++n) {
        int row = (wn << 6) + (n << 4) + (lane & 15);
        int j = ((c << 2) + (lane >> 4)) ^ (lane & 7);
        bfr[n] = *(const bf16x8*)((const char*)Bs + row * 128 + j * 16);
      }
      #pragma unroll
      for (int m = 0; m < 4; ++m)
        #pragma unroll
        for (int n = 0; n < 4; ++n) acc[m][n] = mfma32(af[m], bfr[n], acc[m][n]);
    }
  }

  // fused LoRA tail: one 16x16x32 MFMA step with k=16..31 zeroed (lanes >= 32 hold k>=16)
  {
    bf16x8 a2[4], b2[4];
    bf16x8 z = {0,0,0,0,0,0,0,0};
    #pragma unroll
    for (int m = 0; m < 4; ++m) {
      a2[m] = z; b2[m] = z;
      if (lane < 32) {
        int rowa = (wm << 6) + (m << 4) + (lane & 15);
        a2[m] = *(const bf16x8*)((const char*)As2 + rowa * 32 + (lane >> 4) * 16);
        int rowb = (wn << 6) + (m << 4) + (lane & 15);
        b2[m] = *(const bf16x8*)((const char*)Bs2 + rowb * 32 + (lane >> 4) * 16);
      }
    }
    #pragma unroll
    for (int m = 0; m < 4; ++m)
      #pragma unroll
      for (int n = 0; n < 4; ++n) acc[m][n] = mfma32(a2[m], b2[n], acc[m][n]);
  }

  // epilogue: scatter rows to out[perm[p]]; dummy rows (perm<0) masked
  const int colbase = ((int)bn << 7) + (wn << 6);
  #pragma unroll
  for (int m = 0; m < 4; ++m) {
    #pragma unroll
    for (int reg = 0; reg < 4; ++reg) {
      int p = (int)rowA0 + (wm << 6) + (m << 4) + ((lane >> 4) << 2) + reg;
      int t = perm[p];
      if (t < 0) continue;
      float* orow = out + (size_t)t * NOUT + colbase + (lane & 15);
      #pragma unroll
      for (int n = 0; n < 4; ++n) orow[n << 4] = acc[m][n][reg];
    }
  }
}

// ---------------- launcher ----------------
extern "C" void kernel_launch(void* const* d_in, const int* in_sizes, int n_in,
                              void* d_out, int out_size, void* d_ws, size_t ws_size,
                              hipStream_t stream) {
  const float* x  = (const float*)d_in[0];
  const float* W  = (const float*)d_in[1];
  const float* lA = (const float*)d_in[2];
  const float* Bq = (const float*)d_in[3];
  const float* Bk = (const float*)d_in[4];
  const float* Bv = (const float*)d_in[5];
  const float* sc = (const float*)d_in[6];
  const int* t2s  = (const int*)d_in[7];
  float* out = (float*)d_out;

  char* ws = (char*)d_ws;
  int* perm    = (int*)(ws + 0);                         // 9216 ints
  int* slotarr = (int*)(ws + 36864);                     // 9216 ints
  int* meta    = (int*)(ws + 73728);                     // 64 ints
  unsigned short* abf = (unsigned short*)(ws + 73984);   // 9216*48 bf16
  unsigned short* xb  = (unsigned short*)(ws + 958720);  // 9216*4096 bf16
  unsigned short* Wb  = (unsigned short*)(ws + 76456192);   // 6144*4096 bf16
  unsigned short* Ab  = (unsigned short*)(ws + 126787840);  // 384*4096 bf16
  unsigned short* Bb  = (unsigned short*)(ws + 129933568);  // 8*6144*16 bf16

  hipLaunchKernelGGL(k_sort, dim3(1), dim3(256), 0, stream, t2s, perm, slotarr, meta);
  hipLaunchKernelGGL(k_convert, dim3(2048), dim3(256), 0, stream, W, Wb, NOUT * HID / 8);
  hipLaunchKernelGGL(k_convert, dim3(768), dim3(256), 0, stream, lA, Ab, S_SLOTS * 48 * HID / 8);
  hipLaunchKernelGGL(k_convert_B, dim3(768), dim3(256), 0, stream, Bq, Bk, Bv, Bb);
  hipLaunchKernelGGL(k_convert_x, dim3(TPAD_MAX), dim3(256), 0, stream, x, perm, meta, xb);
  hipLaunchKernelGGL(k_loraA, dim3(288), dim3(256), 0, stream, xb, Ab, sc, slotarr, meta, abf);
  hipLaunchKernelGGL(k_gemm, dim3(3456), dim3(256), 0, stream, xb, Wb, abf, Bb, perm, slotarr, meta, out);
}